// Round 2
// baseline (29.647 us; speedup 1.0000x reference)
//
#include <hip/hip_runtime.h>
#include <cstdint>

#define NRC 4          // real channels
#define NCC 6          // complex channels
#define HD 64
#define CW 16          // z/out row width (floats)

typedef _Float16 half8 __attribute__((ext_vector_type(8)));
typedef float f32x4 __attribute__((ext_vector_type(4)));

__device__ __forceinline__ uint32_t pkh(float a, float b) {
    auto h = __builtin_amdgcn_cvt_pkrtz(a, b);   // __fp16 ext_vector(2), 4 bytes
    return __builtin_bit_cast(uint32_t, h);
}

// LDS word map (uint32 units):
//   [0,    4096)  : W^T f16, 2 layers x 64 rows x 32 words (rotated 16B blocks)
//   [4096, 12288) : h tiles,  4 waves x 64 rows x 32 words (rotated 16B blocks)
//   [12288,12800) : epilogue route buffer, 4 waves x 64 tok x 2 f32
__global__ __launch_bounds__(256, 3) void koop_kernel(
    const float* __restrict__ z,
    const float* __restrict__ W0_r, const float* __restrict__ b0_r,
    const float* __restrict__ Wm_r, const float* __restrict__ bm_r,
    const float* __restrict__ Wl_r, const float* __restrict__ bl_r,
    const float* __restrict__ W0_c, const float* __restrict__ b0_c,
    const float* __restrict__ Wm_c, const float* __restrict__ bm_c,
    const float* __restrict__ Wl_c, const float* __restrict__ bl_c,
    float* __restrict__ out)
{
    __shared__ uint32_t smem[12800];

    const int tid  = threadIdx.x;
    const int lane = tid & 63;
    const int wv   = tid >> 6;
    const int bid  = blockIdx.x;
    const int ch   = bid >> 8;        // 0..9, consecutive blocks share a channel (L2 weight locality)
    const int tile = bid & 255;
    const int t0   = tile * 256;

    const bool isReal = (ch < NRC);
    const int  pc     = ch - NRC;
    const int  No     = isReal ? 1 : 2;

    const float* W0 = isReal ? (W0_r + ch * HD) : (W0_c + pc * HD);
    const float* b0 = isReal ? (b0_r + ch * HD) : (b0_c + pc * HD);
    const float* Wl = isReal ? (Wl_r + ch * HD) : (Wl_c + pc * HD * 2);
    const float* bl = isReal ? (bl_r + ch)      : (bl_c + pc * 2);

    // ---------------- stage W^T (f16) for the two 64x64 layers ----------------
    {
        const int nH = tid & 63;
        const int bb = (tid >> 6) * 2;
        for (int l = 0; l < 2; ++l) {
            const float* Wm = isReal ? (Wm_r + (l * NRC + ch) * HD * HD)
                                     : (Wm_c + (l * NCC + pc) * HD * HD);
            #pragma unroll
            for (int r = 0; r < 2; ++r) {
                const int blk = bb + r;                    // k-block (8 k values)
                const float* src = Wm + blk * 8 * HD + nH; // W[k][nH], stride HD per k
                float v0 = src[0],       v1 = src[HD],     v2 = src[2*HD], v3 = src[3*HD];
                float v4 = src[4*HD],    v5 = src[5*HD],   v6 = src[6*HD], v7 = src[7*HD];
                const int woff = l * 2048 + nH * 32 + (((blk + nH) & 7) << 2);
                uint4 q = { pkh(v0, v1), pkh(v2, v3), pkh(v4, v5), pkh(v6, v7) };
                *(uint4*)&smem[woff] = q;
            }
        }
    }
    __syncthreads();

    // ---------------- per-lane token input ----------------
    const int t = t0 + wv * 64 + lane;
    float xin = 0.f, z1 = 0.f, z2 = 0.f, sval;
    if (isReal) {
        xin = z[t * CW + ch];
        sval = xin;
    } else {
        float2 zz = *(const float2*)(z + t * CW + NRC + 2 * pc);
        z1 = zz.x; z2 = zz.y;
        sval = z1 * z1 + z2 * z2;
    }

    // ---------------- stage 1: h0 = relu(s*W0 + b0), lane = token ----------------
    const int hbase = 4096 + wv * 2048;
    {
        #pragma unroll
        for (int blk = 0; blk < 8; ++blk) {
            uint32_t q0, q1, q2, q3;
            {
                const int n = blk * 8;
                float a0 = fmaxf(fmaf(sval, W0[n+0], b0[n+0]), 0.f);
                float a1 = fmaxf(fmaf(sval, W0[n+1], b0[n+1]), 0.f);
                float a2 = fmaxf(fmaf(sval, W0[n+2], b0[n+2]), 0.f);
                float a3 = fmaxf(fmaf(sval, W0[n+3], b0[n+3]), 0.f);
                float a4 = fmaxf(fmaf(sval, W0[n+4], b0[n+4]), 0.f);
                float a5 = fmaxf(fmaf(sval, W0[n+5], b0[n+5]), 0.f);
                float a6 = fmaxf(fmaf(sval, W0[n+6], b0[n+6]), 0.f);
                float a7 = fmaxf(fmaf(sval, W0[n+7], b0[n+7]), 0.f);
                q0 = pkh(a0, a1); q1 = pkh(a2, a3); q2 = pkh(a4, a5); q3 = pkh(a6, a7);
            }
            const int woff = hbase + lane * 32 + (((blk + lane) & 7) << 2);
            uint4 q = { q0, q1, q2, q3 };
            *(uint4*)&smem[woff] = q;
        }
    }

    const int l15 = lane & 15;
    const int g   = lane >> 4;

    // ---------------- two hidden layers via MFMA ----------------
    // D[nH][tok] = sum_k W^T[nH][k] * h^T[k][tok]; D col = token (lane&15),
    // D row = nH = 16*m + 4*g + reg  -> lane writes 4 consecutive nH of one token.
    f32x4 acc[4][4];
    for (int l = 0; l < 2; ++l) {
        half8 A[4][2];
        #pragma unroll
        for (int m = 0; m < 4; ++m) {
            #pragma unroll
            for (int kt = 0; kt < 2; ++kt) {
                const int row = m * 16 + l15;
                const int blk = kt * 4 + g;
                A[m][kt] = *(const half8*)&smem[l * 2048 + row * 32 + (((blk + row) & 7) << 2)];
            }
        }
        const float* bm = isReal ? (bm_r + (l * NRC + ch) * HD)
                                 : (bm_c + (l * NCC + pc) * HD);
        f32x4 bv[4];
        #pragma unroll
        for (int m = 0; m < 4; ++m)
            bv[m] = *(const f32x4*)(bm + m * 16 + g * 4);

        #pragma unroll
        for (int m = 0; m < 4; ++m)
            #pragma unroll
            for (int tt = 0; tt < 4; ++tt)
                acc[m][tt] = (f32x4){0.f, 0.f, 0.f, 0.f};

        #pragma unroll
        for (int tt = 0; tt < 4; ++tt) {
            #pragma unroll
            for (int kt = 0; kt < 2; ++kt) {
                const int row = tt * 16 + l15;
                const int blk = kt * 4 + g;
                half8 Bf = *(const half8*)&smem[hbase + row * 32 + (((blk + row) & 7) << 2)];
                #pragma unroll
                for (int m = 0; m < 4; ++m)
                    acc[m][tt] = __builtin_amdgcn_mfma_f32_16x16x32_f16(A[m][kt], Bf, acc[m][tt], 0, 0, 0);
            }
        }

        // epilogue: bias + relu + pack f16 + write back to h tile (token-major, rotated blocks)
        #pragma unroll
        for (int tt = 0; tt < 4; ++tt) {
            const int row = tt * 16 + l15;
            #pragma unroll
            for (int m = 0; m < 4; ++m) {
                f32x4 v = acc[m][tt];
                float a0 = fmaxf(v[0] + bv[m][0], 0.f);
                float a1 = fmaxf(v[1] + bv[m][1], 0.f);
                float a2 = fmaxf(v[2] + bv[m][2], 0.f);
                float a3 = fmaxf(v[3] + bv[m][3], 0.f);
                const int blk  = 2 * m + (g >> 1);
                const int woff = hbase + row * 32 + (((blk + row) & 7) << 2) + (g & 1) * 2;
                uint2 q = { pkh(a0, a1), pkh(a2, a3) };
                *(uint2*)&smem[woff] = q;
            }
        }
    }

    // ---------------- final layer: out_raw[tok][o] via MFMA (o rows 0..No-1) ----------------
    half8 Af[2];
    #pragma unroll
    for (int kt = 0; kt < 2; ++kt) {
        half8 a;
        #pragma unroll
        for (int e = 0; e < 8; ++e) {
            const int k = kt * 32 + g * 8 + e;
            float w = (l15 < No) ? Wl[k * No + l15] : 0.f;
            a[e] = (_Float16)w;
        }
        Af[kt] = a;
    }
    f32x4 accf[4];
    #pragma unroll
    for (int tt = 0; tt < 4; ++tt) accf[tt] = (f32x4){0.f, 0.f, 0.f, 0.f};
    #pragma unroll
    for (int tt = 0; tt < 4; ++tt) {
        #pragma unroll
        for (int kt = 0; kt < 2; ++kt) {
            const int row = tt * 16 + l15;
            const int blk = kt * 4 + g;
            half8 Bf = *(const half8*)&smem[hbase + row * 32 + (((blk + row) & 7) << 2)];
            accf[tt] = __builtin_amdgcn_mfma_f32_16x16x32_f16(Af[kt], Bf, accf[tt], 0, 0, 0);
        }
    }

    // ---------------- route results to lane = token, then elementwise epilogue ----------------
    float* smf = (float*)smem;
    const int obase = 12288 + wv * 128;
    if (g == 0) {  // lanes 0..15 hold rows 0..3 (= output o index in reg)
        #pragma unroll
        for (int tt = 0; tt < 4; ++tt) {
            const int tok = tt * 16 + l15;
            if (isReal) {
                smf[obase + tok * 2] = accf[tt][0] + bl[0];
            } else {
                float2 mo = { accf[tt][0] + bl[0], accf[tt][1] + bl[1] };
                *(float2*)&smf[obase + tok * 2] = mo;
            }
        }
    }
    __syncthreads();

    if (isReal) {
        float lam = smf[obase + lane * 2];
        out[t * CW + ch] = xin * lam;
    } else {
        float2 mo = *(const float2*)&smf[obase + lane * 2];
        float ex = __expf(mo.x);
        float mc = ex * __cosf(mo.y);
        float ms = ex * __sinf(mo.y);
        float o1 =  z1 * mc + z2 * ms;
        float o2 =  z2 * mc - z1 * ms;
        *(float2*)(out + t * CW + NRC + 2 * pc) = make_float2(o1, o2);
    }
}

extern "C" void kernel_launch(void* const* d_in, const int* in_sizes, int n_in,
                              void* d_out, int out_size, void* d_ws, size_t ws_size,
                              hipStream_t stream) {
    (void)in_sizes; (void)n_in; (void)d_ws; (void)ws_size; (void)out_size;
    const float* z    = (const float*)d_in[0];
    const float* W0_r = (const float*)d_in[1];
    const float* b0_r = (const float*)d_in[2];
    const float* Wm_r = (const float*)d_in[3];
    const float* bm_r = (const float*)d_in[4];
    const float* Wl_r = (const float*)d_in[5];
    const float* bl_r = (const float*)d_in[6];
    const float* W0_c = (const float*)d_in[7];
    const float* b0_c = (const float*)d_in[8];
    const float* Wm_c = (const float*)d_in[9];
    const float* bm_c = (const float*)d_in[10];
    const float* Wl_c = (const float*)d_in[11];
    const float* bl_c = (const float*)d_in[12];
    float* outp = (float*)d_out;

    dim3 grid(2560), block(256);
    koop_kernel<<<grid, block, 0, stream>>>(z, W0_r, b0_r, Wm_r, bm_r, Wl_r, bl_r,
                                            W0_c, b0_c, Wm_c, bm_c, Wl_c, bl_c, outp);
}

// Round 3
// 26.786 us; speedup vs baseline: 1.1068x; 1.1068x over previous
//
#include <hip/hip_runtime.h>
#include <cstdint>

#define NRC 4          // real channels
#define NCC 6          // complex channels
#define HD 64
#define CW 16          // z/out row width (floats)

typedef _Float16 half8 __attribute__((ext_vector_type(8)));
typedef float f32x4 __attribute__((ext_vector_type(4)));

__device__ __forceinline__ uint32_t pkh(float a, float b) {
    auto h = __builtin_amdgcn_cvt_pkrtz(a, b);   // __fp16 ext_vector(2), 4 bytes
    return __builtin_bit_cast(uint32_t, h);
}

// LDS word map (uint32 units), 10240 words = 40960 B -> exactly 4 blocks/CU:
//   [0,    8192)  : h tiles, wave wv at [wv*2048, wv*2048+2048)  (64 rows x 32 words, rotated 16B blocks)
//                   layer-1 W^T is STAGED TEMPORARILY at [0,2048) (wave0's h area),
//                   read into registers by all waves before wave0 overwrites it.
//   [8192, 10240) : layer-2 W^T f16, persistent (64 rows x 32 words, rotated)
//   route buffer  : reuses own wave's h words [hbase, hbase+128) (dead after final B-reads)
__global__ __launch_bounds__(256, 4) void koop_kernel(
    const float* __restrict__ z,
    const float* __restrict__ W0_r, const float* __restrict__ b0_r,
    const float* __restrict__ Wm_r, const float* __restrict__ bm_r,
    const float* __restrict__ Wl_r, const float* __restrict__ bl_r,
    const float* __restrict__ W0_c, const float* __restrict__ b0_c,
    const float* __restrict__ Wm_c, const float* __restrict__ bm_c,
    const float* __restrict__ Wl_c, const float* __restrict__ bl_c,
    float* __restrict__ out)
{
    __shared__ uint32_t smem[10240];

    const int tid  = threadIdx.x;
    const int lane = tid & 63;
    const int wv   = tid >> 6;
    const int bid  = blockIdx.x;
    const int ch   = bid >> 8;        // consecutive blocks share a channel (L2 weight locality)
    const int tile = bid & 255;
    const int t0   = tile * 256;

    const bool isReal = (ch < NRC);
    const int  pc     = ch - NRC;
    const int  No     = isReal ? 1 : 2;

    const float* W0 = isReal ? (W0_r + ch * HD) : (W0_c + pc * HD);
    const float* b0 = isReal ? (b0_r + ch * HD) : (b0_c + pc * HD);
    const float* Wl = isReal ? (Wl_r + ch * HD) : (Wl_c + pc * HD * 2);
    const float* bl = isReal ? (bl_r + ch)      : (bl_c + pc * 2);

    // ---------------- stage W^T (f16): L1 -> [0,2048) temp, L2 -> [8192,10240) ----------------
    {
        const int nH = tid & 63;
        const int bb = (tid >> 6) * 2;
        for (int l = 0; l < 2; ++l) {
            const float* Wm = isReal ? (Wm_r + (l * NRC + ch) * HD * HD)
                                     : (Wm_c + (l * NCC + pc) * HD * HD);
            const int base = l ? 8192 : 0;
            #pragma unroll
            for (int r = 0; r < 2; ++r) {
                const int blk = bb + r;                    // k-block (8 k values)
                const float* src = Wm + blk * 8 * HD + nH; // W[k][nH], stride HD per k
                float v0 = src[0],       v1 = src[HD],     v2 = src[2*HD], v3 = src[3*HD];
                float v4 = src[4*HD],    v5 = src[5*HD],   v6 = src[6*HD], v7 = src[7*HD];
                const int woff = base + nH * 32 + (((blk + nH) & 7) << 2);
                uint4 q = { pkh(v0, v1), pkh(v2, v3), pkh(v4, v5), pkh(v6, v7) };
                *(uint4*)&smem[woff] = q;
            }
        }
    }
    __syncthreads();

    const int l15 = lane & 15;
    const int g   = lane >> 4;

    // ---------------- pre-read layer-1 A fragments into registers ----------------
    half8 A1[4][2];
    #pragma unroll
    for (int m = 0; m < 4; ++m) {
        #pragma unroll
        for (int kt = 0; kt < 2; ++kt) {
            const int row = m * 16 + l15;
            const int blk = kt * 4 + g;
            A1[m][kt] = *(const half8*)&smem[row * 32 + (((blk + row) & 7) << 2)];
        }
    }
    __syncthreads();   // all A1 reads done before wave0 overwrites [0,2048)

    // ---------------- per-lane token input ----------------
    const int t = t0 + wv * 64 + lane;
    float xin = 0.f, z1 = 0.f, z2 = 0.f, sval;
    if (isReal) {
        xin = z[t * CW + ch];
        sval = xin;
    } else {
        float2 zz = *(const float2*)(z + t * CW + NRC + 2 * pc);
        z1 = zz.x; z2 = zz.y;
        sval = z1 * z1 + z2 * z2;
    }

    // ---------------- stage 1: h0 = relu(s*W0 + b0), lane = token ----------------
    const int hbase = wv * 2048;
    {
        #pragma unroll
        for (int blk = 0; blk < 8; ++blk) {
            uint32_t q0, q1, q2, q3;
            {
                const int n = blk * 8;
                float a0 = fmaxf(fmaf(sval, W0[n+0], b0[n+0]), 0.f);
                float a1 = fmaxf(fmaf(sval, W0[n+1], b0[n+1]), 0.f);
                float a2 = fmaxf(fmaf(sval, W0[n+2], b0[n+2]), 0.f);
                float a3 = fmaxf(fmaf(sval, W0[n+3], b0[n+3]), 0.f);
                float a4 = fmaxf(fmaf(sval, W0[n+4], b0[n+4]), 0.f);
                float a5 = fmaxf(fmaf(sval, W0[n+5], b0[n+5]), 0.f);
                float a6 = fmaxf(fmaf(sval, W0[n+6], b0[n+6]), 0.f);
                float a7 = fmaxf(fmaf(sval, W0[n+7], b0[n+7]), 0.f);
                q0 = pkh(a0, a1); q1 = pkh(a2, a3); q2 = pkh(a4, a5); q3 = pkh(a6, a7);
            }
            const int woff = hbase + lane * 32 + (((blk + lane) & 7) << 2);
            uint4 q = { q0, q1, q2, q3 };
            *(uint4*)&smem[woff] = q;
        }
    }

    // ---------------- two hidden layers via MFMA ----------------
    // D[nH][tok]; D col = token (lane&15), D row = nH = 16*m + 4*g + reg.
    // Tokens processed in two halves of 32 -> acc is 32 regs, bias folded into init.
    half8 A[4][2];
    #pragma unroll
    for (int m = 0; m < 4; ++m)
        #pragma unroll
        for (int kt = 0; kt < 2; ++kt)
            A[m][kt] = A1[m][kt];

    for (int l = 0; l < 2; ++l) {
        if (l == 1) {
            #pragma unroll
            for (int m = 0; m < 4; ++m) {
                #pragma unroll
                for (int kt = 0; kt < 2; ++kt) {
                    const int row = m * 16 + l15;
                    const int blk = kt * 4 + g;
                    A[m][kt] = *(const half8*)&smem[8192 + row * 32 + (((blk + row) & 7) << 2)];
                }
            }
        }
        const float* bm = isReal ? (bm_r + (l * NRC + ch) * HD)
                                 : (bm_c + (l * NCC + pc) * HD);
        f32x4 bv[4];
        #pragma unroll
        for (int m = 0; m < 4; ++m)
            bv[m] = *(const f32x4*)(bm + m * 16 + g * 4);

        #pragma unroll
        for (int th = 0; th < 2; ++th) {
            f32x4 acc[4][2];
            #pragma unroll
            for (int m = 0; m < 4; ++m)
                #pragma unroll
                for (int u = 0; u < 2; ++u)
                    acc[m][u] = bv[m];                    // bias folded into C

            #pragma unroll
            for (int u = 0; u < 2; ++u) {
                const int tt = th * 2 + u;
                #pragma unroll
                for (int kt = 0; kt < 2; ++kt) {
                    const int row = tt * 16 + l15;
                    const int blk = kt * 4 + g;
                    half8 Bf = *(const half8*)&smem[hbase + row * 32 + (((blk + row) & 7) << 2)];
                    #pragma unroll
                    for (int m = 0; m < 4; ++m)
                        acc[m][u] = __builtin_amdgcn_mfma_f32_16x16x32_f16(A[m][kt], Bf, acc[m][u], 0, 0, 0);
                }
            }

            // epilogue: relu + pack f16 + write back (rows of this half only; disjoint
            // from the other half's B-read rows, wave-local ordering suffices)
            #pragma unroll
            for (int u = 0; u < 2; ++u) {
                const int tt = th * 2 + u;
                const int row = tt * 16 + l15;
                #pragma unroll
                for (int m = 0; m < 4; ++m) {
                    f32x4 v = acc[m][u];
                    float a0 = fmaxf(v[0], 0.f);
                    float a1 = fmaxf(v[1], 0.f);
                    float a2 = fmaxf(v[2], 0.f);
                    float a3 = fmaxf(v[3], 0.f);
                    const int blk  = 2 * m + (g >> 1);
                    const int woff = hbase + row * 32 + (((blk + row) & 7) << 2) + (g & 1) * 2;
                    uint2 q = { pkh(a0, a1), pkh(a2, a3) };
                    *(uint2*)&smem[woff] = q;
                }
            }
        }
    }

    // ---------------- final layer: out_raw[o][tok] via MFMA (o rows, bias in init) ----------------
    half8 Af[2];
    #pragma unroll
    for (int kt = 0; kt < 2; ++kt) {
        half8 a;
        #pragma unroll
        for (int e = 0; e < 8; ++e) {
            const int k = kt * 32 + g * 8 + e;
            float w = (l15 < No) ? Wl[k * No + l15] : 0.f;
            a[e] = (_Float16)w;
        }
        Af[kt] = a;
    }
    f32x4 cf0 = (f32x4){0.f, 0.f, 0.f, 0.f};
    if (g == 0) { cf0[0] = bl[0]; if (!isReal) cf0[1] = bl[1]; }
    f32x4 accf[4];
    #pragma unroll
    for (int tt = 0; tt < 4; ++tt) accf[tt] = cf0;
    #pragma unroll
    for (int tt = 0; tt < 4; ++tt) {
        #pragma unroll
        for (int kt = 0; kt < 2; ++kt) {
            const int row = tt * 16 + l15;
            const int blk = kt * 4 + g;
            half8 Bf = *(const half8*)&smem[hbase + row * 32 + (((blk + row) & 7) << 2)];
            accf[tt] = __builtin_amdgcn_mfma_f32_16x16x32_f16(Af[kt], Bf, accf[tt], 0, 0, 0);
        }
    }

    // ---------------- route results to lane = token (wave-local, reuse own h words) ----------------
    float* smf = (float*)smem;
    const int obase = hbase;            // words [hbase, hbase+128): 64 tok x 2 f32
    if (g == 0) {
        #pragma unroll
        for (int tt = 0; tt < 4; ++tt) {
            const int tok = tt * 16 + l15;
            if (isReal) {
                smf[obase + tok * 2] = accf[tt][0];
            } else {
                float2 mo = { accf[tt][0], accf[tt][1] };
                *(float2*)&smf[obase + tok * 2] = mo;
            }
        }
    }
    __asm__ volatile("s_waitcnt lgkmcnt(0)" ::: "memory");
    __builtin_amdgcn_sched_barrier(0);

    if (isReal) {
        float lam = smf[obase + lane * 2];
        out[t * CW + ch] = xin * lam;
    } else {
        float2 mo = *(const float2*)&smf[obase + lane * 2];
        float ex = __expf(mo.x);
        float mc = ex * __cosf(mo.y);
        float ms = ex * __sinf(mo.y);
        float o1 =  z1 * mc + z2 * ms;
        float o2 =  z2 * mc - z1 * ms;
        *(float2*)(out + t * CW + NRC + 2 * pc) = make_float2(o1, o2);
    }
}

extern "C" void kernel_launch(void* const* d_in, const int* in_sizes, int n_in,
                              void* d_out, int out_size, void* d_ws, size_t ws_size,
                              hipStream_t stream) {
    (void)in_sizes; (void)n_in; (void)d_ws; (void)ws_size; (void)out_size;
    const float* z    = (const float*)d_in[0];
    const float* W0_r = (const float*)d_in[1];
    const float* b0_r = (const float*)d_in[2];
    const float* Wm_r = (const float*)d_in[3];
    const float* bm_r = (const float*)d_in[4];
    const float* Wl_r = (const float*)d_in[5];
    const float* bl_r = (const float*)d_in[6];
    const float* W0_c = (const float*)d_in[7];
    const float* b0_c = (const float*)d_in[8];
    const float* Wm_c = (const float*)d_in[9];
    const float* bm_c = (const float*)d_in[10];
    const float* Wl_c = (const float*)d_in[11];
    const float* bl_c = (const float*)d_in[12];
    float* outp = (float*)d_out;

    dim3 grid(2560), block(256);
    koop_kernel<<<grid, block, 0, stream>>>(z, W0_r, b0_r, Wm_r, bm_r, Wl_r, bl_r,
                                            W0_c, b0_c, Wm_c, bm_c, Wl_c, bl_c, outp);
}